// Round 1
// baseline (232.413 us; speedup 1.0000x reference)
//
#include <hip/hip_runtime.h>
#include <hip/hip_bf16.h>
#include <math.h>

// TreeLSTM, B=8, L=4096, D=300, H=128, 12 levels. Round 7:
// - convx fused into leaf (fp32 x staged via GLDS with XOR-swizzled source,
//   in-register v_cvt_pk_bf16_f32 -> MFMA fragments). Kills 21MB write + 21MB
//   re-read + one launch.
// - Levels 6..12 fused into ONE kernel (64 blocks, device-scope atomic spin
//   barrier between levels; W-slice stays in 160 VGPRs across all 7 levels).
// - Fast sigmoid/tanh via v_rcp_f32 (div-free, inf-safe).
// Levels 1..5 keep the R6 weight-stationary kernel (chunk-major layouts).

typedef __attribute__((ext_vector_type(8))) short bfrag8;   // 8 bf16 = 4 VGPRs
typedef __attribute__((ext_vector_type(4))) float f32x4;

__device__ __forceinline__ float rcpf(float x) { return __builtin_amdgcn_rcpf(x); }
__device__ __forceinline__ float sigf(float x) { return rcpf(1.0f + __expf(-x)); }
__device__ __forceinline__ float tanh_f(float x) {
    float e = __expf(2.0f * x);              // x>>0: e=inf -> rcp=0 -> 1 ; x<<0: e=0 -> -1
    return 1.0f - 2.0f * rcpf(e + 1.0f);
}
__device__ __forceinline__ short f2bf(float f) {
    __hip_bfloat16 h = __float2bfloat16(f);
    return *reinterpret_cast<short*>(&h);
}
__device__ __forceinline__ bfrag8 pack8(f32x4 a, f32x4 b) {
    union { int i[4]; bfrag8 v; } u;
    asm("v_cvt_pk_bf16_f32 %0, %1, %2" : "=v"(u.i[0]) : "v"(a[0]), "v"(a[1]));
    asm("v_cvt_pk_bf16_f32 %0, %1, %2" : "=v"(u.i[1]) : "v"(a[2]), "v"(a[3]));
    asm("v_cvt_pk_bf16_f32 %0, %1, %2" : "=v"(u.i[2]) : "v"(b[0]), "v"(b[1]));
    asm("v_cvt_pk_bf16_f32 %0, %1, %2" : "=v"(u.i[3]) : "v"(b[2]), "v"(b[3]));
    return u.v;
}
#define GLDS(gp, lp) __builtin_amdgcn_global_load_lds( \
    (const __attribute__((address_space(1))) void*)(gp), \
    (__attribute__((address_space(3))) void*)(lp), 16, 0, 0)

// ---------------- weight reorder (once, tiny) + barrier zero ----------------
// Wcat_ch : chunk layout [c:0..31][n:0..640) ; n = g*128+h ; k<128 -> W_l, else W_r.
// Wleaf_ch: chunk layout [c:0..39][n:0..256) ; k<300 valid else 0.
__global__ __launch_bounds__(256) void reorder_kernel(
    const float* __restrict__ W_l, const float* __restrict__ W_r,
    const float* __restrict__ W_leaf,
    short* __restrict__ Wcat_ch, short* __restrict__ Wleaf_ch,
    unsigned int* __restrict__ bar)
{
    int idx = blockIdx.x * 256 + threadIdx.x;
    if (blockIdx.x == 0 && threadIdx.x < 16) bar[threadIdx.x] = 0u;
    if (idx < 163840) {
        int n = idx >> 8, k = idx & 255;
        float v = (k < 128) ? W_l[k * 640 + n] : W_r[(k - 128) * 640 + n];
        Wcat_ch[(((size_t)(k >> 3)) * 640 + n) * 8 + (k & 7)] = f2bf(v);
        return;
    }
    idx -= 163840;
    if (idx < 81920) {
        int n = idx / 320, k = idx - n * 320;
        short v = (k < 300) ? f2bf(W_leaf[k * 256 + n]) : (short)0;
        Wleaf_ch[(((size_t)(k >> 3)) * 256 + n) * 8 + (k & 7)] = v;
    }
}

// ---------------- leaf (fused x-convert): [32768,320fp32]@[320,256bf16] ----------------
// Tiles 128x128, grid (256, 2). Per iter: K=64. A staged as fp32 with XOR-swizzled
// SOURCE addresses (LDS stays linear for GLDS); fragments read as 2x f32x4 and
// packed to bf16 in-register. B (W_leaf) staged in chunk units as before.
__global__ __launch_bounds__(256) void leaf_kernel(
    const float* __restrict__ x, const short* __restrict__ Bw,
    const float* __restrict__ bleaf,
    short* __restrict__ hD,       // level-1 A, chunk layout [32][16384] units
    float* __restrict__ cD)       // [32768][128] fp32
{
    __shared__ float Als[128 * 64];     // 32 KB: [row][16 units of 4 floats], swizzled
    __shared__ short Bls[8 * 128 * 8];  // 16 KB: [c][n] units
    const int tid  = threadIdx.x;
    const int w    = tid >> 6, lane = tid & 63;
    const int quad = lane >> 4, l16 = lane & 15;
    const int mBlk = blockIdx.x * 128, nBlk = blockIdx.y * 128;
    const int waveM = (w >> 1) * 64, waveN = (w & 1) * 64;

    f32x4 acc[4][4] = {};
    const f32x4 zero4 = {0.f, 0.f, 0.f, 0.f};

    for (int c = 0; c < 5; ++c) {           // K = 5 * 64 = 320 (300 + zero pad)
        const int k0 = c * 64;
        // ---- stage A: 8 GLDS/wave, 4 rows each; source-swizzled so LDS[row][q]
        //      holds global unit (q&8)|((q&7)^(row&7))  -> frag reads conflict-free
        {
            const int q_lds = lane & 15;
            const int rsub  = lane >> 4;
            #pragma unroll
            for (int g = 0; g < 8; ++g) {
                int row = w * 32 + g * 4 + rsub;
                int q_g = (q_lds & 8) | ((q_lds & 7) ^ (row & 7));
                if (c < 4 || q_g < 11) {
                    GLDS(x + (size_t)(mBlk + row) * 300 + k0 + q_g * 4,
                         (char*)Als + (w * 32 + g * 4) * 256);
                } else {
                    *(f32x4*)((char*)Als + row * 256 + q_lds * 16) = zero4;  // pad k=300..319
                }
            }
        }
        // ---- stage B: 4 GLDS/wave (8 chunk-rows x 128 n = 16 KB)
        #pragma unroll
        for (int g2 = 0; g2 < 4; ++g2) {
            int u = w * 4 + g2;   // 0..15 -> cc = u>>1, half = u&1
            GLDS(Bw + ((size_t)(c * 8 + (u >> 1)) * 256 + nBlk + (u & 1) * 64 + lane) * 8,
                 (char*)Bls + u * 1024);
        }
        __syncthreads();
        #pragma unroll
        for (int ks = 0; ks < 2; ++ks) {
            const int ca = ks * 4 + quad;
            bfrag8 af[4], bf4[4];
            #pragma unroll
            for (int i = 0; i < 4; ++i) {
                int r  = waveM + i * 16 + l16;
                int u0 = 2 * ca, u1 = 2 * ca + 1;
                int s0 = (u0 & 8) | ((u0 & 7) ^ (r & 7));
                int s1 = (u1 & 8) | ((u1 & 7) ^ (r & 7));
                f32x4 a0 = *(const f32x4*)(Als + r * 64 + s0 * 4);
                f32x4 a1 = *(const f32x4*)(Als + r * 64 + s1 * 4);
                af[i] = pack8(a0, a1);
            }
            #pragma unroll
            for (int jn = 0; jn < 4; ++jn)
                bf4[jn] = *(const bfrag8*)(Bls + (ca * 128 + waveN + jn * 16 + l16) * 8);
            #pragma unroll
            for (int i = 0; i < 4; ++i)
                #pragma unroll
                for (int jn = 0; jn < 4; ++jn)
                    acc[i][jn] = __builtin_amdgcn_mfma_f32_16x16x32_bf16(
                                     af[i], bf4[jn], acc[i][jn], 0, 0, 0);
        }
        __syncthreads();
    }

    #pragma unroll
    for (int i = 0; i < 4; ++i) {
        int row0 = mBlk + waveM + i * 16 + quad * 4;
        #pragma unroll
        for (int jn = 0; jn < 4; ++jn) {
            int col = nBlk + waveN + jn * 16 + l16;
            float bv = bleaf[col];
            #pragma unroll
            for (int rg = 0; rg < 4; ++rg) {
                float v = acc[i][jn][rg] + bv;
                int m = row0 + rg;
                if (nBlk == 0) {
                    int hc = col;
                    hD[(((size_t)((m & 1) * 16 + (hc >> 3))) * 16384 + (m >> 1)) * 8
                       + (hc & 7)] = f2bf(v);
                } else {
                    cD[(size_t)m * 128 + (col - 128)] = v;
                }
            }
        }
    }
}

// ---------------- weight-stationary level kernel (levels 1..5) ----------------
__global__ __launch_bounds__(256, 2) void level_ws_kernel(
    const short* __restrict__ A,      // [32][M] chunk units
    const float* __restrict__ cprev,  // [2M][128] fp32
    const short* __restrict__ Wch,    // [32][640] chunk units
    const float* __restrict__ bias,   // [640]
    short* __restrict__ hout, float* __restrict__ cout_,
    int M)
{
    __shared__ short Als[32 * 64 * 8];   // 32 KB, [c][row]
    const int tid  = threadIdx.x;
    const int w    = tid >> 6, lane = tid & 63;
    const int quad = lane >> 4, l16 = lane & 15;
    const int j  = blockIdx.y;
    const int tb = blockIdx.x * 64;
    const int h  = j * 16 + l16;

    {
        int row = tb + lane; if (row >= M) row = 0;
        #pragma unroll
        for (int s = 0; s < 8; ++s)
            GLDS(A + ((size_t)(s * 4 + w) * M + row) * 8,
                 (char*)Als + (s * 4 + w) * 1024);
    }

    bfrag8 Wfr[5][8];
    #pragma unroll
    for (int g = 0; g < 5; ++g)
        #pragma unroll
        for (int s = 0; s < 8; ++s)
            Wfr[g][s] = *(const bfrag8*)(Wch + ((size_t)(s * 4 + quad) * 640
                                                + g * 128 + h) * 8);
    const float bi  = bias[h],       bfl = bias[128 + h], bfr_ = bias[256 + h];
    const float bo  = bias[384 + h], bg  = bias[512 + h];

    __syncthreads();

    f32x4 acc[5] = {};
    #pragma unroll
    for (int s = 0; s < 8; ++s) {
        bfrag8 af = *(const bfrag8*)(Als + ((s * 4 + quad) * 64 + w * 16 + l16) * 8);
        #pragma unroll
        for (int g = 0; g < 5; ++g)
            acc[g] = __builtin_amdgcn_mfma_f32_16x16x32_bf16(af, Wfr[g][s], acc[g], 0, 0, 0);
    }

    const int Mn = M >> 1;
    #pragma unroll
    for (int rg = 0; rg < 4; ++rg) {
        int m = tb + w * 16 + quad * 4 + rg;
        if (m < M) {
            float gi  = acc[0][rg] + bi;
            float gfl = acc[1][rg] + bfl;
            float gfr = acc[2][rg] + bfr_;
            float go  = acc[3][rg] + bo;
            float gg  = acc[4][rg] + bg;
            float cl  = cprev[(size_t)(2 * m) * 128 + h];
            float cr  = cprev[(size_t)(2 * m + 1) * 128 + h];
            float cn  = sigf(gfl) * cl + sigf(gfr) * cr + sigf(gi) * tanh_f(gg);
            float hn  = sigf(go) * tanh_f(cn);
            hout[(((size_t)((m & 1) * 16 + (h >> 3))) * Mn + (m >> 1)) * 8
                 + (h & 7)] = f2bf(hn);
            cout_[(size_t)m * 128 + h] = cn;
        }
    }
}

// ---------------- fused tail: levels 6..12 in one dispatch ----------------
// Grid (8,8) = 64 blocks (trivially co-resident at 2 blocks/CU). W stays in
// VGPRs across all 7 levels; device-scope atomic spin barrier between levels.
__global__ __launch_bounds__(256, 2) void tail_kernel(
    short* __restrict__ hA, short* __restrict__ hB,
    float* __restrict__ c0, float* __restrict__ c1,
    const short* __restrict__ Wch, const float* __restrict__ bias,
    float* __restrict__ out, unsigned int* __restrict__ bar)
{
    __shared__ short Als[32 * 64 * 8];
    const int tid  = threadIdx.x;
    const int w    = tid >> 6, lane = tid & 63;
    const int quad = lane >> 4, l16 = lane & 15;
    const int j  = blockIdx.y;
    const int tb = blockIdx.x * 64;
    const int h  = j * 16 + l16;

    bfrag8 Wfr[5][8];
    #pragma unroll
    for (int g = 0; g < 5; ++g)
        #pragma unroll
        for (int s = 0; s < 8; ++s)
            Wfr[g][s] = *(const bfrag8*)(Wch + ((size_t)(s * 4 + quad) * 640
                                                + g * 128 + h) * 8);
    const float bi  = bias[h],       bfl = bias[128 + h], bfr_ = bias[256 + h];
    const float bo  = bias[384 + h], bg  = bias[512 + h];

    for (int lev = 6; lev <= 12; ++lev) {
        const int Mo = 32768 >> lev;                 // output rows this level
        const short* A     = (lev & 1) ? hA : hB;    // input  h  (prev level out)
        const float* cprev = (lev & 1) ? c0 : c1;    // input  c
        short* hout  = (lev & 1) ? hB : hA;          // output h
        float* coutp = (lev & 1) ? c1 : c0;          // output c
        const bool active = (tb < Mo);

        if (active) {
            int row = tb + lane; if (row >= Mo) row = 0;
            #pragma unroll
            for (int s = 0; s < 8; ++s)
                GLDS(A + ((size_t)(s * 4 + w) * Mo + row) * 8,
                     (char*)Als + (s * 4 + w) * 1024);
        }
        __syncthreads();

        if (active) {
            f32x4 acc[5] = {};
            #pragma unroll
            for (int s = 0; s < 8; ++s) {
                bfrag8 af = *(const bfrag8*)(Als + ((s * 4 + quad) * 64 + w * 16 + l16) * 8);
                #pragma unroll
                for (int g = 0; g < 5; ++g)
                    acc[g] = __builtin_amdgcn_mfma_f32_16x16x32_bf16(af, Wfr[g][s], acc[g], 0, 0, 0);
            }
            const int Mn = Mo >> 1;
            #pragma unroll
            for (int rg = 0; rg < 4; ++rg) {
                int m = tb + w * 16 + quad * 4 + rg;
                if (m < Mo) {
                    float gi  = acc[0][rg] + bi;
                    float gfl = acc[1][rg] + bfl;
                    float gfr = acc[2][rg] + bfr_;
                    float go  = acc[3][rg] + bo;
                    float gg  = acc[4][rg] + bg;
                    float cl  = cprev[(size_t)(2 * m) * 128 + h];
                    float cr  = cprev[(size_t)(2 * m + 1) * 128 + h];
                    float cn  = sigf(gfl) * cl + sigf(gfr) * cr + sigf(gi) * tanh_f(gg);
                    float hn  = sigf(go) * tanh_f(cn);
                    if (lev == 12) {
                        out[(size_t)m * 128 + h] = hn;
                    } else {
                        hout[(((size_t)((m & 1) * 16 + (h >> 3))) * Mn + (m >> 1)) * 8
                             + (h & 7)] = f2bf(hn);
                        coutp[(size_t)m * 128 + h] = cn;
                    }
                }
            }
        }

        if (lev < 12) {
            __threadfence();                          // release my h/c stores
            __syncthreads();
            if (tid == 0) {
                atomicAdd(&bar[lev], 1u);
                while (__hip_atomic_load(&bar[lev], __ATOMIC_RELAXED,
                                         __HIP_MEMORY_SCOPE_AGENT) < 64u)
                    __builtin_amdgcn_s_sleep(4);
            }
            __syncthreads();
            __threadfence();                          // acquire: invalidate before reads
        }
    }
}

extern "C" void kernel_launch(void* const* d_in, const int* in_sizes, int n_in,
                              void* d_out, int out_size, void* d_ws, size_t ws_size,
                              hipStream_t stream)
{
    const float* x      = (const float*)d_in[0];
    const float* W_leaf = (const float*)d_in[1];
    const float* b_leaf = (const float*)d_in[2];
    const float* W_l    = (const float*)d_in[3];
    const float* W_r    = (const float*)d_in[4];
    const float* b      = (const float*)d_in[5];
    float* out = (float*)d_out;

    // workspace (~38.5 MB)
    char* p = (char*)d_ws;
    short* hA    = (short*)p; p += (size_t)32 * 16384 * 16 + 1024; //  8.4 MB
    short* hB    = (short*)p; p += (size_t)32 * 8192 * 16 + 1024;  //  4.2 MB
    float* c0    = (float*)p; p += (size_t)32768 * 128 * 4;        // 16.8 MB
    float* c1    = (float*)p; p += (size_t)16384 * 128 * 4;        //  8.4 MB
    short* WcatC = (short*)p; p += (size_t)32 * 640 * 16;          // 320 KB
    short* WlfC  = (short*)p; p += (size_t)40 * 256 * 16;          // 160 KB
    unsigned int* bar = (unsigned int*)p; p += 64;

    reorder_kernel<<<960, 256, 0, stream>>>(W_l, W_r, W_leaf, WcatC, WlfC, bar);
    leaf_kernel<<<dim3(256, 2), 256, 0, stream>>>(x, WlfC, b_leaf, hA, c0);

    const short* hin = hA; const float* cin = c0;
    int M = 16384;
    for (int lev = 1; lev <= 5; ++lev) {
        short* ho = (lev & 1) ? hB : hA;
        float* co = (lev & 1) ? c1 : c0;
        level_ws_kernel<<<dim3(M / 64, 8), 256, 0, stream>>>(
            hin, cin, WcatC, b, ho, co, M);
        hin = ho; cin = co;
        M >>= 1;
    }
    // after lev 5: hin = hB, cin = c1, M = 512
    tail_kernel<<<dim3(8, 8), 256, 0, stream>>>(hA, hB, c0, c1, WcatC, b, out, bar);
}

// Round 3
// 186.809 us; speedup vs baseline: 1.2441x; 1.2441x over previous
//
#include <hip/hip_runtime.h>
#include <hip/hip_bf16.h>
#include <math.h>

// TreeLSTM, B=8, L=4096, D=300, H=128, 12 levels. Round 9:
// - R8 post-mortem: finish_kernel's IN-PLACE LDS c had a RAW hazard across
//   lane-quads (quad q reads c rows [8q,8q+8) interleaved with quads writing
//   rows [4q',4q'+4) -> rows 4..7 read stale-free but ALREADY-OVERWRITTEN).
//   Fix: double-buffer c in LDS (cA 64KB <-> cB 32KB ping-pong), like h.
// - Levels 6..8 per-level launches (R7's fused-tail spin barrier cost 79us of
//   agent-scope coherence traffic; launches are ~2.5us each).
// - Levels 9..12 fused in ONE single-block finisher (512 thr, wave j = h-group
//   j, W in VGPRs, h ping/pong LDS, c ping/pong LDS, __syncthreads only).
// - Keeps R7 wins: leaf fused with x fp32->bf16 (GLDS swizzled source,
//   v_cvt_pk_bf16_f32), div-free sigmoid/tanh.

typedef __attribute__((ext_vector_type(8))) short bfrag8;   // 8 bf16 = 4 VGPRs
typedef __attribute__((ext_vector_type(4))) float f32x4;

__device__ __forceinline__ float rcpf(float x) { return __builtin_amdgcn_rcpf(x); }
__device__ __forceinline__ float sigf(float x) { return rcpf(1.0f + __expf(-x)); }
__device__ __forceinline__ float tanh_f(float x) {
    float e = __expf(2.0f * x);              // x>>0: e=inf -> rcp=0 -> 1 ; x<<0: e=0 -> -1
    return 1.0f - 2.0f * rcpf(e + 1.0f);
}
__device__ __forceinline__ short f2bf(float f) {
    __hip_bfloat16 h = __float2bfloat16(f);
    return *reinterpret_cast<short*>(&h);
}
__device__ __forceinline__ bfrag8 pack8(f32x4 a, f32x4 b) {
    union { int i[4]; bfrag8 v; } u;
    asm("v_cvt_pk_bf16_f32 %0, %1, %2" : "=v"(u.i[0]) : "v"(a[0]), "v"(a[1]));
    asm("v_cvt_pk_bf16_f32 %0, %1, %2" : "=v"(u.i[1]) : "v"(a[2]), "v"(a[3]));
    asm("v_cvt_pk_bf16_f32 %0, %1, %2" : "=v"(u.i[2]) : "v"(b[0]), "v"(b[1]));
    asm("v_cvt_pk_bf16_f32 %0, %1, %2" : "=v"(u.i[3]) : "v"(b[2]), "v"(b[3]));
    return u.v;
}
#define GLDS(gp, lp) __builtin_amdgcn_global_load_lds( \
    (const __attribute__((address_space(1))) void*)(gp), \
    (__attribute__((address_space(3))) void*)(lp), 16, 0, 0)

// ---------------- weight reorder (once, tiny) ----------------
// Wcat_ch : chunk layout [c:0..31][n:0..640) ; n = g*128+h ; k<128 -> W_l, else W_r.
// Wleaf_ch: chunk layout [c:0..39][n:0..256) ; k<300 valid else 0.
__global__ __launch_bounds__(256) void reorder_kernel(
    const float* __restrict__ W_l, const float* __restrict__ W_r,
    const float* __restrict__ W_leaf,
    short* __restrict__ Wcat_ch, short* __restrict__ Wleaf_ch)
{
    int idx = blockIdx.x * 256 + threadIdx.x;
    if (idx < 163840) {
        int n = idx >> 8, k = idx & 255;
        float v = (k < 128) ? W_l[k * 640 + n] : W_r[(k - 128) * 640 + n];
        Wcat_ch[(((size_t)(k >> 3)) * 640 + n) * 8 + (k & 7)] = f2bf(v);
        return;
    }
    idx -= 163840;
    if (idx < 81920) {
        int n = idx / 320, k = idx - n * 320;
        short v = (k < 300) ? f2bf(W_leaf[k * 256 + n]) : (short)0;
        Wleaf_ch[(((size_t)(k >> 3)) * 256 + n) * 8 + (k & 7)] = v;
    }
}

// ---------------- leaf (fused x-convert): [32768,320fp32]@[320,256bf16] ----------------
__global__ __launch_bounds__(256) void leaf_kernel(
    const float* __restrict__ x, const short* __restrict__ Bw,
    const float* __restrict__ bleaf,
    short* __restrict__ hD,       // level-1 A, chunk layout [32][16384] units
    float* __restrict__ cD)       // [32768][128] fp32
{
    __shared__ float Als[128 * 64];     // 32 KB: [row][16 units of 4 floats], swizzled
    __shared__ short Bls[8 * 128 * 8];  // 16 KB: [c][n] units
    const int tid  = threadIdx.x;
    const int w    = tid >> 6, lane = tid & 63;
    const int quad = lane >> 4, l16 = lane & 15;
    const int mBlk = blockIdx.x * 128, nBlk = blockIdx.y * 128;
    const int waveM = (w >> 1) * 64, waveN = (w & 1) * 64;

    f32x4 acc[4][4] = {};
    const f32x4 zero4 = {0.f, 0.f, 0.f, 0.f};

    for (int c = 0; c < 5; ++c) {           // K = 5 * 64 = 320 (300 + zero pad)
        const int k0 = c * 64;
        {
            const int q_lds = lane & 15;
            const int rsub  = lane >> 4;
            #pragma unroll
            for (int g = 0; g < 8; ++g) {
                int row = w * 32 + g * 4 + rsub;
                int q_g = (q_lds & 8) | ((q_lds & 7) ^ (row & 7));
                if (c < 4 || q_g < 11) {
                    GLDS(x + (size_t)(mBlk + row) * 300 + k0 + q_g * 4,
                         (char*)Als + (w * 32 + g * 4) * 256);
                } else {
                    *(f32x4*)((char*)Als + row * 256 + q_lds * 16) = zero4;  // pad k=300..319
                }
            }
        }
        #pragma unroll
        for (int g2 = 0; g2 < 4; ++g2) {
            int u = w * 4 + g2;   // 0..15 -> cc = u>>1, half = u&1
            GLDS(Bw + ((size_t)(c * 8 + (u >> 1)) * 256 + nBlk + (u & 1) * 64 + lane) * 8,
                 (char*)Bls + u * 1024);
        }
        __syncthreads();
        #pragma unroll
        for (int ks = 0; ks < 2; ++ks) {
            const int ca = ks * 4 + quad;
            bfrag8 af[4], bf4[4];
            #pragma unroll
            for (int i = 0; i < 4; ++i) {
                int r  = waveM + i * 16 + l16;
                int u0 = 2 * ca, u1 = 2 * ca + 1;
                int s0 = (u0 & 8) | ((u0 & 7) ^ (r & 7));
                int s1 = (u1 & 8) | ((u1 & 7) ^ (r & 7));
                f32x4 a0 = *(const f32x4*)(Als + r * 64 + s0 * 4);
                f32x4 a1 = *(const f32x4*)(Als + r * 64 + s1 * 4);
                af[i] = pack8(a0, a1);
            }
            #pragma unroll
            for (int jn = 0; jn < 4; ++jn)
                bf4[jn] = *(const bfrag8*)(Bls + (ca * 128 + waveN + jn * 16 + l16) * 8);
            #pragma unroll
            for (int i = 0; i < 4; ++i)
                #pragma unroll
                for (int jn = 0; jn < 4; ++jn)
                    acc[i][jn] = __builtin_amdgcn_mfma_f32_16x16x32_bf16(
                                     af[i], bf4[jn], acc[i][jn], 0, 0, 0);
        }
        __syncthreads();
    }

    #pragma unroll
    for (int i = 0; i < 4; ++i) {
        int row0 = mBlk + waveM + i * 16 + quad * 4;
        #pragma unroll
        for (int jn = 0; jn < 4; ++jn) {
            int col = nBlk + waveN + jn * 16 + l16;
            float bv = bleaf[col];
            #pragma unroll
            for (int rg = 0; rg < 4; ++rg) {
                float v = acc[i][jn][rg] + bv;
                int m = row0 + rg;
                if (nBlk == 0) {
                    int hc = col;
                    hD[(((size_t)((m & 1) * 16 + (hc >> 3))) * 16384 + (m >> 1)) * 8
                       + (hc & 7)] = f2bf(v);
                } else {
                    cD[(size_t)m * 128 + (col - 128)] = v;
                }
            }
        }
    }
}

// ---------------- weight-stationary level kernel (levels 1..8) ----------------
__global__ __launch_bounds__(256, 2) void level_ws_kernel(
    const short* __restrict__ A,      // [32][M] chunk units
    const float* __restrict__ cprev,  // [2M][128] fp32
    const short* __restrict__ Wch,    // [32][640] chunk units
    const float* __restrict__ bias,   // [640]
    short* __restrict__ hout, float* __restrict__ cout_,
    int M)
{
    __shared__ short Als[32 * 64 * 8];   // 32 KB, [c][row]
    const int tid  = threadIdx.x;
    const int w    = tid >> 6, lane = tid & 63;
    const int quad = lane >> 4, l16 = lane & 15;
    const int j  = blockIdx.y;
    const int tb = blockIdx.x * 64;
    const int h  = j * 16 + l16;

    {
        int row = tb + lane; if (row >= M) row = 0;
        #pragma unroll
        for (int s = 0; s < 8; ++s)
            GLDS(A + ((size_t)(s * 4 + w) * M + row) * 8,
                 (char*)Als + (s * 4 + w) * 1024);
    }

    bfrag8 Wfr[5][8];
    #pragma unroll
    for (int g = 0; g < 5; ++g)
        #pragma unroll
        for (int s = 0; s < 8; ++s)
            Wfr[g][s] = *(const bfrag8*)(Wch + ((size_t)(s * 4 + quad) * 640
                                                + g * 128 + h) * 8);
    const float bi  = bias[h],       bfl = bias[128 + h], bfr_ = bias[256 + h];
    const float bo  = bias[384 + h], bg  = bias[512 + h];

    __syncthreads();

    f32x4 acc[5] = {};
    #pragma unroll
    for (int s = 0; s < 8; ++s) {
        bfrag8 af = *(const bfrag8*)(Als + ((s * 4 + quad) * 64 + w * 16 + l16) * 8);
        #pragma unroll
        for (int g = 0; g < 5; ++g)
            acc[g] = __builtin_amdgcn_mfma_f32_16x16x32_bf16(af, Wfr[g][s], acc[g], 0, 0, 0);
    }

    const int Mn = M >> 1;
    #pragma unroll
    for (int rg = 0; rg < 4; ++rg) {
        int m = tb + w * 16 + quad * 4 + rg;
        if (m < M) {
            float gi  = acc[0][rg] + bi;
            float gfl = acc[1][rg] + bfl;
            float gfr = acc[2][rg] + bfr_;
            float go  = acc[3][rg] + bo;
            float gg  = acc[4][rg] + bg;
            float cl  = cprev[(size_t)(2 * m) * 128 + h];
            float cr  = cprev[(size_t)(2 * m + 1) * 128 + h];
            float cn  = sigf(gfl) * cl + sigf(gfr) * cr + sigf(gi) * tanh_f(gg);
            float hn  = sigf(go) * tanh_f(cn);
            hout[(((size_t)((m & 1) * 16 + (h >> 3))) * Mn + (m >> 1)) * 8
                 + (h & 7)] = f2bf(hn);
            cout_[(size_t)m * 128 + h] = cn;
        }
    }
}

// ---------------- single-block finisher: levels 9..12 ----------------
// Input: lev-8 output h (128 rows, chunk layout [32][64] units, 32 KB) and
// c (128x128 f32, 64 KB). One block, 512 threads; wave j owns h-group j
// (W-slice in VGPRs). h ping/pongs hP<->hQ; c ping/pongs cA<->cB (NOT
// in-place: R8's in-place update had a cross-quad RAW hazard within a wave).
// Only __syncthreads between levels. LDS: 32+16+64+32 = 144 KB.
__global__ __launch_bounds__(512) void finish_kernel(
    const short* __restrict__ hin,   // [32][64] units (128-row chunk layout)
    const float* __restrict__ cin,   // [128][128] f32
    const short* __restrict__ Wch, const float* __restrict__ bias,
    float* __restrict__ out)         // [8][128]
{
    __shared__ short hP[32 * 64 * 8];   // 32 KB ping
    __shared__ short hQ[32 * 32 * 8];   // 16 KB pong
    __shared__ float cA[128 * 128];     // 64 KB: c in at t=0/2, c out at t=1
    __shared__ float cB[64 * 128];      // 32 KB: c out at t=0/2, c in at t=1/3
    const int tid  = threadIdx.x;
    const int w    = tid >> 6, lane = tid & 63;
    const int quad = lane >> 4, l16 = lane & 15;
    const int h    = w * 16 + l16;      // wave = h-group

    // stage h: 2048 units, 4 GLDS per wave (each = 64 lanes x 16B contiguous)
    #pragma unroll
    for (int g = 0; g < 4; ++g)
        GLDS(hin + ((size_t)((g * 8 + w) * 64 + lane)) * 8,
             (char*)hP + ((g * 8 + w) * 64) * 16);
    // stage c: 64 KB linear, 8 GLDS per wave
    #pragma unroll
    for (int g = 0; g < 8; ++g)
        GLDS(cin + ((size_t)((g * 8 + w) * 64 + lane)) * 4,
             (char*)cA + ((g * 8 + w) * 64) * 16);

    // W fragments for this wave's h-group (overlaps the staging)
    bfrag8 Wfr[5][8];
    #pragma unroll
    for (int g = 0; g < 5; ++g)
        #pragma unroll
        for (int s = 0; s < 8; ++s)
            Wfr[g][s] = *(const bfrag8*)(Wch + ((size_t)(s * 4 + quad) * 640
                                                + g * 128 + h) * 8);
    const float bi  = bias[h],       bfl = bias[128 + h], bfr_ = bias[256 + h];
    const float bo  = bias[384 + h], bg  = bias[512 + h];

    __syncthreads();

    #pragma unroll
    for (int t = 0; t < 4; ++t) {              // levels 9..12; Mo = output rows
        const int Mo = 64 >> t;                // 64, 32, 16, 8
        const short* hsrc = (t & 1) ? hQ : hP; // [32][Mo] units
        short* hdst       = (t & 1) ? hP : hQ; // [32][Mo/2] units
        const float* cread = (t & 1) ? cB : cA;
        float*       cwrite = (t & 1) ? cA : cB;
        const int nrt = (Mo + 15) >> 4;

        for (int rt = 0; rt < nrt; ++rt) {
            f32x4 acc[5] = {};
            #pragma unroll
            for (int s = 0; s < 8; ++s) {
                bfrag8 af = *(const bfrag8*)(hsrc + ((s * 4 + quad) * Mo
                                                     + rt * 16 + l16) * 8);
                #pragma unroll
                for (int g = 0; g < 5; ++g)
                    acc[g] = __builtin_amdgcn_mfma_f32_16x16x32_bf16(
                                 af, Wfr[g][s], acc[g], 0, 0, 0);
            }
            #pragma unroll
            for (int rg = 0; rg < 4; ++rg) {
                int m = rt * 16 + quad * 4 + rg;
                if (m < Mo) {
                    float gi  = acc[0][rg] + bi;
                    float gfl = acc[1][rg] + bfl;
                    float gfr = acc[2][rg] + bfr_;
                    float go  = acc[3][rg] + bo;
                    float gg  = acc[4][rg] + bg;
                    float cl  = cread[(2 * m) * 128 + h];
                    float cr  = cread[(2 * m + 1) * 128 + h];
                    float cn  = sigf(gfl) * cl + sigf(gfr) * cr + sigf(gi) * tanh_f(gg);
                    float hn  = sigf(go) * tanh_f(cn);
                    if (t == 3) {
                        out[(size_t)m * 128 + h] = hn;
                    } else {
                        hdst[(((m & 1) * 16 + (h >> 3)) * (Mo >> 1) + (m >> 1)) * 8
                             + (h & 7)] = f2bf(hn);
                        cwrite[m * 128 + h] = cn;
                    }
                }
            }
        }
        __syncthreads();
    }
}

extern "C" void kernel_launch(void* const* d_in, const int* in_sizes, int n_in,
                              void* d_out, int out_size, void* d_ws, size_t ws_size,
                              hipStream_t stream)
{
    const float* x      = (const float*)d_in[0];
    const float* W_leaf = (const float*)d_in[1];
    const float* b_leaf = (const float*)d_in[2];
    const float* W_l    = (const float*)d_in[3];
    const float* W_r    = (const float*)d_in[4];
    const float* b      = (const float*)d_in[5];
    float* out = (float*)d_out;

    // workspace (~38.5 MB)
    char* p = (char*)d_ws;
    short* hA    = (short*)p; p += (size_t)32 * 16384 * 16 + 1024; //  8.4 MB
    short* hB    = (short*)p; p += (size_t)32 * 8192 * 16 + 1024;  //  4.2 MB
    float* c0    = (float*)p; p += (size_t)32768 * 128 * 4;        // 16.8 MB
    float* c1    = (float*)p; p += (size_t)16384 * 128 * 4;        //  8.4 MB
    short* WcatC = (short*)p; p += (size_t)32 * 640 * 16;          // 320 KB
    short* WlfC  = (short*)p; p += (size_t)40 * 256 * 16;          // 160 KB

    reorder_kernel<<<960, 256, 0, stream>>>(W_l, W_r, W_leaf, WcatC, WlfC);
    leaf_kernel<<<dim3(256, 2), 256, 0, stream>>>(x, WlfC, b_leaf, hA, c0);

    const short* hin = hA; const float* cin = c0;
    int M = 16384;
    for (int lev = 1; lev <= 8; ++lev) {
        short* ho = (lev & 1) ? hB : hA;
        float* co = (lev & 1) ? c1 : c0;
        level_ws_kernel<<<dim3((M + 63) / 64, 8), 256, 0, stream>>>(
            hin, cin, WcatC, b, ho, co, M);
        hin = ho; cin = co;
        M >>= 1;
    }
    // after lev 8: hin = hA ([32][64] units), cin = c0 ([128][128] f32)
    finish_kernel<<<1, 512, 0, stream>>>(hA, c0, WcatC, b, out);
}